// Round 1
// baseline (800.207 us; speedup 1.0000x reference)
//
#include <hip/hip_runtime.h>
#include <stdint.h>

// FrontierExplorationPolicy: bit-parallel binary morphology.
// frontier = (map[:,1]==0); eroded = erosion(frontier, disk(10));
// goal = dilation(eroded, disk(1)) - eroded   (border of eroded region)
//
// disk(10) decomposes per-row: for dy in [-10,10], horizontal half-width
// w(|dy|) = floor(sqrt(100-dy^2)) = [10,9,9,9,9,8,8,7,6,4,0].
// So eroded[i] = AND_dy HorErode_{w(|dy|)}(f[i+dy]).
// disk(1) is the plus shape {center, up, down, left, right}.

#define MDIM 960
#define NW 15                 // 64-bit words per row (960 = 15*64)
#define TILE 8                // output rows per block
#define RSTAGE (TILE + 22)    // staged input rows (need +/-11)
#define EROWS (TILE + 2)      // eroded rows needed (+/-1 for dilation)
#define NTHREADS 256
#define NBATCH 8
#define NCHAN 24
#define EXPLORED_CH 1

__global__ __launch_bounds__(NTHREADS) void frontier_kernel(
    const float* __restrict__ in, float* __restrict__ out)
{
    __shared__ uint64_t sF[RSTAGE][NW];        // packed frontier rows (w=0)
    __shared__ uint64_t sH[6][RSTAGE][NW];     // hor. erosions w=4,6,7,8,9,10
    __shared__ uint64_t sE[EROWS][NW];         // eroded rows

    const int bx   = blockIdx.x;
    const int b    = bx / (MDIM / TILE);
    const int tile = bx % (MDIM / TILE);
    const int i0   = tile * TILE;
    const int tid  = threadIdx.x;
    const int lane = tid & 63;
    const int wv   = tid >> 6;

    const size_t chan = (size_t)MDIM * MDIM;
    const float* src = in + ((size_t)b * NCHAN + EXPLORED_CH) * chan;

    // ---- Phase 1: pack frontier bits (bit=1 where map==0). Coalesced:
    // each lane reads 1 float, __ballot assembles the 64-bit word.
    for (int t = wv; t < RSTAGE * NW; t += NTHREADS / 64) {
        int l = t / NW, wd = t % NW;
        int g = i0 - 11 + l;
        uint64_t m = 0;
        if (g >= 0 && g < MDIM) {
            float v = src[(size_t)g * MDIM + wd * 64 + lane];
            m = __ballot(v == 0.0f);
        }
        if (lane == 0) sF[l][wd] = m;
    }
    __syncthreads();

    // ---- Phase 2: horizontal erosions. 3-word register window; chained
    // erode-by-1. Edge pollution reaches <=10 bits into the outer words;
    // the center word only depends on the inner 20 bits of neighbors -> exact.
    for (int t = tid; t < RSTAGE * NW; t += NTHREADS) {
        int l = t / NW, wd = t % NW;
        uint64_t a  = (wd > 0)      ? sF[l][wd - 1] : 0ull;
        uint64_t bb = sF[l][wd];
        uint64_t c  = (wd < NW - 1) ? sF[l][wd + 1] : 0ull;
        #pragma unroll
        for (int k = 1; k <= 10; ++k) {
            uint64_t da = (a >> 1) | (bb << 63);
            uint64_t db = (bb >> 1) | (c << 63);
            uint64_t dc = (c >> 1);
            uint64_t ua = (a << 1);
            uint64_t ub = (bb << 1) | (a >> 63);
            uint64_t uc = (c << 1) | (bb >> 63);
            a  &= da & ua;
            bb &= db & ub;
            c  &= dc & uc;
            if (k == 4)  sH[0][l][wd] = bb;
            if (k == 6)  sH[1][l][wd] = bb;
            if (k == 7)  sH[2][l][wd] = bb;
            if (k == 8)  sH[3][l][wd] = bb;
            if (k == 9)  sH[4][l][wd] = bb;
            if (k == 10) sH[5][l][wd] = bb;
        }
    }
    __syncthreads();

    // ---- Phase 3: vertical AND over 21 rows -> eroded rows i0-1 .. i0+TILE.
    // LDS row l corresponds to global row i0-11+l; eroded row r is global
    // i0-1+r, so offset dy maps to l = r+10+dy.
    for (int t = tid; t < EROWS * NW; t += NTHREADS) {
        int r = t / NW, wd = t % NW;
        uint64_t e = sF[r][wd] & sF[r + 20][wd];                 // |dy|=10, w=0
        e &= sH[0][r + 1][wd] & sH[0][r + 19][wd];               // |dy|=9, w=4
        e &= sH[1][r + 2][wd] & sH[1][r + 18][wd];               // |dy|=8, w=6
        e &= sH[2][r + 3][wd] & sH[2][r + 17][wd];               // |dy|=7, w=7
        e &= sH[3][r + 4][wd] & sH[3][r + 16][wd];               // |dy|=6, w=8
        e &= sH[3][r + 5][wd] & sH[3][r + 15][wd];               // |dy|=5, w=8
        e &= sH[4][r + 6][wd] & sH[4][r + 14][wd];               // |dy|=4, w=9
        e &= sH[4][r + 7][wd] & sH[4][r + 13][wd];               // |dy|=3, w=9
        e &= sH[4][r + 8][wd] & sH[4][r + 12][wd];               // |dy|=2, w=9
        e &= sH[4][r + 9][wd] & sH[4][r + 11][wd];               // |dy|=1, w=9
        e &= sH[5][r + 10][wd];                                  // dy=0, w=10
        sE[r][wd] = e;
    }
    __syncthreads();

    // ---- Phase 4: goal = (E | N | S | W | E-shifts) & ~E, write float4.
    float* dst = out + (size_t)b * chan;
    for (int t = tid; t < TILE * (MDIM / 4); t += NTHREADS) {
        int ro = t / (MDIM / 4), c4 = t % (MDIM / 4);
        int c0 = c4 * 4;
        float vj[4];
        #pragma unroll
        for (int j = 0; j < 4; ++j) {
            int col = c0 + j;
            int wd = col >> 6, sh = col & 63;
            unsigned e  = (unsigned)((sE[ro + 1][wd] >> sh) & 1);
            unsigned n  = (unsigned)((sE[ro    ][wd] >> sh) & 1);
            unsigned s  = (unsigned)((sE[ro + 2][wd] >> sh) & 1);
            unsigned lf = (col > 0)
                ? (unsigned)((sE[ro + 1][(col - 1) >> 6] >> ((col - 1) & 63)) & 1) : 0u;
            unsigned rt = (col < MDIM - 1)
                ? (unsigned)((sE[ro + 1][(col + 1) >> 6] >> ((col + 1) & 63)) & 1) : 0u;
            unsigned d = e | n | s | lf | rt;
            vj[j] = (float)(d & (e ^ 1u));
        }
        float4 v = make_float4(vj[0], vj[1], vj[2], vj[3]);
        *(float4*)(dst + (size_t)(i0 + ro) * MDIM + c0) = v;
    }
}

extern "C" void kernel_launch(void* const* d_in, const int* in_sizes, int n_in,
                              void* d_out, int out_size, void* d_ws, size_t ws_size,
                              hipStream_t stream)
{
    const float* mapf = (const float*)d_in[0];
    float* out = (float*)d_out;
    dim3 grid(NBATCH * (MDIM / TILE));   // 8 * 120 = 960 blocks
    frontier_kernel<<<grid, NTHREADS, 0, stream>>>(mapf, out);
}

// Round 2
// 753.993 us; speedup vs baseline: 1.0613x; 1.0613x over previous
//
#include <hip/hip_runtime.h>
#include <stdint.h>

// FrontierExplorationPolicy: bit-parallel binary morphology, 2-kernel split.
// K1 (pack): frontier bits = (map[:,1]==0) ballot-packed to u64 bitmap in d_ws.
// K2 (morph): eroded = erosion(frontier, disk(10)) via per-row horizontal
//             erosions (widths [10,9,9,9,9,8,8,7,6,4,0] for |dy|=0..10) and a
//             21-row vertical AND; goal = plus-dilation(eroded) & ~eroded.

#define MDIM 960
#define NW 15                 // 64-bit words per row (960 = 15*64)
#define TILE 8                // output rows per block (K2)
#define RSTAGE (TILE + 22)    // staged input rows (need +/-11)
#define EROWS (TILE + 2)      // eroded rows needed (+/-1 for dilation)
#define NTHREADS 256
#define NBATCH 8
#define NCHAN 24
#define EXPLORED_CH 1
#define ROWS_TOTAL (NBATCH * MDIM)          // 7680 packed rows
#define PACK_BLOCKS 480                      // 1920 waves * 4 rows = 7680

// ---- Kernel 1: pack (map==0) bits, one row per wave-iteration, 15 loads
// in flight per row so the loop is BW-bound, not latency-bound.
__global__ __launch_bounds__(NTHREADS) void frontier_pack_kernel(
    const float* __restrict__ in, uint64_t* __restrict__ ws)
{
    const int wave = blockIdx.x * (NTHREADS / 64) + (threadIdx.x >> 6);
    const int lane = threadIdx.x & 63;
    #pragma unroll
    for (int rr = 0; rr < 4; ++rr) {
        const int R = wave * 4 + rr;            // 0..7679
        const int b = R / MDIM, row = R % MDIM;
        const float* src = in + ((size_t)b * NCHAN + EXPLORED_CH) * MDIM * MDIM
                              + (size_t)row * MDIM;
        uint64_t w[NW];
        #pragma unroll
        for (int j = 0; j < NW; ++j) {
            float v = src[j * 64 + lane];
            w[j] = __ballot(v == 0.0f);
        }
        if (lane == 0) {
            uint64_t* dst = ws + (size_t)R * NW;
            #pragma unroll
            for (int j = 0; j < NW; ++j) dst[j] = w[j];
        }
    }
}

// ---- Kernel 2: morphology on the packed bitmap.
__global__ __launch_bounds__(NTHREADS) void frontier_morph_kernel(
    const uint64_t* __restrict__ ws, float* __restrict__ out)
{
    __shared__ uint64_t sF[RSTAGE][NW];        // packed frontier rows (w=0)
    __shared__ uint64_t sH[6][RSTAGE][NW];     // hor. erosions w=4,6,7,8,9,10
    __shared__ uint64_t sE[EROWS][NW];         // eroded rows

    const int bx   = blockIdx.x;
    const int b    = bx / (MDIM / TILE);
    const int tile = bx % (MDIM / TILE);
    const int i0   = tile * TILE;
    const int tid  = threadIdx.x;

    // ---- Phase 1: stage packed rows (contiguous u64 loads, L2-resident).
    const uint64_t* pk = ws + (size_t)b * MDIM * NW;
    for (int t = tid; t < RSTAGE * NW; t += NTHREADS) {
        int l = t / NW, wd = t % NW;
        int g = i0 - 11 + l;
        sF[l][wd] = (g >= 0 && g < MDIM) ? pk[(size_t)g * NW + wd] : 0ull;
    }
    __syncthreads();

    // ---- Phase 2: horizontal erosions. 3-word register window; chained
    // erode-by-1. Edge pollution reaches <=10 bits into the outer words;
    // the center word only depends on the inner bits of neighbors -> exact.
    for (int t = tid; t < RSTAGE * NW; t += NTHREADS) {
        int l = t / NW, wd = t % NW;
        uint64_t a  = (wd > 0)      ? sF[l][wd - 1] : 0ull;
        uint64_t bb = sF[l][wd];
        uint64_t c  = (wd < NW - 1) ? sF[l][wd + 1] : 0ull;
        #pragma unroll
        for (int k = 1; k <= 10; ++k) {
            uint64_t da = (a >> 1) | (bb << 63);
            uint64_t db = (bb >> 1) | (c << 63);
            uint64_t dc = (c >> 1);
            uint64_t ua = (a << 1);
            uint64_t ub = (bb << 1) | (a >> 63);
            uint64_t uc = (c << 1) | (bb >> 63);
            a  &= da & ua;
            bb &= db & ub;
            c  &= dc & uc;
            if (k == 4)  sH[0][l][wd] = bb;
            if (k == 6)  sH[1][l][wd] = bb;
            if (k == 7)  sH[2][l][wd] = bb;
            if (k == 8)  sH[3][l][wd] = bb;
            if (k == 9)  sH[4][l][wd] = bb;
            if (k == 10) sH[5][l][wd] = bb;
        }
    }
    __syncthreads();

    // ---- Phase 3: vertical AND over 21 rows -> eroded rows i0-1 .. i0+TILE.
    // LDS row l is global row i0-11+l; eroded row r is global i0-1+r.
    for (int t = tid; t < EROWS * NW; t += NTHREADS) {
        int r = t / NW, wd = t % NW;
        uint64_t e = sF[r][wd] & sF[r + 20][wd];                 // |dy|=10, w=0
        e &= sH[0][r + 1][wd] & sH[0][r + 19][wd];               // |dy|=9, w=4
        e &= sH[1][r + 2][wd] & sH[1][r + 18][wd];               // |dy|=8, w=6
        e &= sH[2][r + 3][wd] & sH[2][r + 17][wd];               // |dy|=7, w=7
        e &= sH[3][r + 4][wd] & sH[3][r + 16][wd];               // |dy|=6, w=8
        e &= sH[3][r + 5][wd] & sH[3][r + 15][wd];               // |dy|=5, w=8
        e &= sH[4][r + 6][wd] & sH[4][r + 14][wd];               // |dy|=4, w=9
        e &= sH[4][r + 7][wd] & sH[4][r + 13][wd];               // |dy|=3, w=9
        e &= sH[4][r + 8][wd] & sH[4][r + 12][wd];               // |dy|=2, w=9
        e &= sH[4][r + 9][wd] & sH[4][r + 11][wd];               // |dy|=1, w=9
        e &= sH[5][r + 10][wd];                                  // dy=0, w=10
        sE[r][wd] = e;
    }
    __syncthreads();

    // ---- Phase 4: goal = (E | N | S | W | E-shifts) & ~E, write float4.
    float* dst = out + (size_t)b * MDIM * MDIM;
    for (int t = tid; t < TILE * (MDIM / 4); t += NTHREADS) {
        int ro = t / (MDIM / 4), c4 = t % (MDIM / 4);
        int c0 = c4 * 4;
        float vj[4];
        #pragma unroll
        for (int j = 0; j < 4; ++j) {
            int col = c0 + j;
            int wd = col >> 6, sh = col & 63;
            unsigned e  = (unsigned)((sE[ro + 1][wd] >> sh) & 1);
            unsigned n  = (unsigned)((sE[ro    ][wd] >> sh) & 1);
            unsigned s  = (unsigned)((sE[ro + 2][wd] >> sh) & 1);
            unsigned lf = (col > 0)
                ? (unsigned)((sE[ro + 1][(col - 1) >> 6] >> ((col - 1) & 63)) & 1) : 0u;
            unsigned rt = (col < MDIM - 1)
                ? (unsigned)((sE[ro + 1][(col + 1) >> 6] >> ((col + 1) & 63)) & 1) : 0u;
            unsigned d = e | n | s | lf | rt;
            vj[j] = (float)(d & (e ^ 1u));
        }
        float4 v = make_float4(vj[0], vj[1], vj[2], vj[3]);
        *(float4*)(dst + (size_t)(i0 + ro) * MDIM + c0) = v;
    }
}

extern "C" void kernel_launch(void* const* d_in, const int* in_sizes, int n_in,
                              void* d_out, int out_size, void* d_ws, size_t ws_size,
                              hipStream_t stream)
{
    const float* mapf = (const float*)d_in[0];
    float* out = (float*)d_out;
    uint64_t* ws = (uint64_t*)d_ws;   // 7680*15*8 = 921,600 B used

    frontier_pack_kernel<<<dim3(PACK_BLOCKS), NTHREADS, 0, stream>>>(mapf, ws);
    frontier_morph_kernel<<<dim3(NBATCH * (MDIM / TILE)), NTHREADS, 0, stream>>>(ws, out);
}